// Round 8
// baseline (272.223 us; speedup 1.0000x reference)
//
#include <hip/hip_runtime.h>

#define IMW 1024
#define IMH 1024
#define NB  8
#define HALF 25
#define SLAB 8
#define NSLAB (IMH / SLAB)   // 128
#define STRIP 16
#define NCELL 64

#define W_R ((double)0.2989f)
#define W_G ((double)0.5870f)
#define W_B ((double)0.1140f)
#define INV_AREA (1.0 / 2601.0)

// 51-window sum at pixel p from inclusive row cumsum C[0..IMW-1], reflect pad.
__device__ __forceinline__ double wsum(const double* __restrict__ C, int p) {
    int a = p + HALF; if (a > IMW - 1) a = IMW - 1;
    int b = p - HALF - 1;
    double s = C[a] - (b >= 0 ? C[b] : 0.0);
    if (p <= HALF - 1)      s += C[HALF - p] - C[0];                        // i<0 mirrored
    if (p >= IMW - HALF)    s += C[IMW - 2] - C[2*IMW - 2 - HALF - 1 - p];  // i>=IMW mirrored
    return s;
}

// init 64 min-cells (all-ones) and 64 max-cells (zero); gray>=0 so bit-order == double order
__global__ void k0_init(unsigned long long* cells) {
    cells[threadIdx.x] = ~0ULL;          // min cells
    cells[NCELL + threadIdx.x] = 0ULL;   // max cells
}

// One block per 8-row slab. For each row: horizontal cumsum scan (as before),
// 51-window sums h1,h2; accumulate vertical in-slab running sum in registers
// and store C_loc = per-slab-inclusive vertical cumsum of {h1,h2}.
__global__ __launch_bounds__(256) void k1_slab(const float* __restrict__ in,
                                               double2* __restrict__ hp,
                                               unsigned long long* __restrict__ cells) {
    __shared__ double cs1[IMW];
    __shared__ double cs2[IMW];
    __shared__ double wt1[4], wt2[4];
    const int blk = blockIdx.x;                  // 0 .. NB*NSLAB-1
    const int b = blk / NSLAB;
    const int s = blk % NSLAB;
    const int r0 = s * SLAB;
    const int t = threadIdx.x;
    const int lane = t & 63, w = t >> 6;

    double acc1[4] = {0.0, 0.0, 0.0, 0.0};
    double acc2[4] = {0.0, 0.0, 0.0, 0.0};
    double lmin = 1e300, lmax = -1e300;

    for (int r = 0; r < SLAB; r++) {
        const int row = r0 + r;
        const long long base = ((long long)b * IMH + row) * IMW;

        // 4 consecutive pixels per thread = 12 floats = 3x float4
        const float4* p4 = (const float4*)(in + base * 3);
        float4 f0 = p4[3*t], f1 = p4[3*t+1], f2 = p4[3*t+2];
        double g0 = (double)f0.x*W_R + (double)f0.y*W_G + (double)f0.z*W_B;
        double g1 = (double)f0.w*W_R + (double)f1.x*W_G + (double)f1.y*W_B;
        double g2 = (double)f1.z*W_R + (double)f1.w*W_G + (double)f2.x*W_B;
        double g3 = (double)f2.y*W_R + (double)f2.z*W_G + (double)f2.w*W_B;

        double l1_0 = g0, l1_1 = l1_0 + g1, l1_2 = l1_1 + g2, l1_3 = l1_2 + g3;
        double q0 = g0*g0, q1 = g1*g1, q2 = g2*g2, q3 = g3*g3;
        double l2_0 = q0, l2_1 = l2_0 + q1, l2_2 = l2_1 + q2, l2_3 = l2_2 + q3;

        lmin = fmin(lmin, fmin(fmin(g0, g1), fmin(g2, g3)));
        lmax = fmax(lmax, fmax(fmax(g0, g1), fmax(g2, g3)));

        // wave-level inclusive scan of per-thread totals
        double v1 = l1_3, v2 = l2_3;
        for (int off = 1; off < 64; off <<= 1) {
            double u1 = __shfl_up(v1, off);
            double u2 = __shfl_up(v2, off);
            if (lane >= off) { v1 += u1; v2 += u2; }
        }
        __syncthreads();                 // cs/wt free from previous row
        if (lane == 63) { wt1[w] = v1; wt2[w] = v2; }
        __syncthreads();
        double e1 = v1 - l1_3, e2 = v2 - l2_3;
        for (int j = 0; j < w; j++) { e1 += wt1[j]; e2 += wt2[j]; }

        double2* c1 = (double2*)&cs1[4*t];
        double2* c2 = (double2*)&cs2[4*t];
        c1[0] = make_double2(e1 + l1_0, e1 + l1_1);
        c1[1] = make_double2(e1 + l1_2, e1 + l1_3);
        c2[0] = make_double2(e2 + l2_0, e2 + l2_1);
        c2[1] = make_double2(e2 + l2_2, e2 + l2_3);
        __syncthreads();                 // cs ready

        #pragma unroll
        for (int k = 0; k < 4; k++) {
            int p = t + 256 * k;
            acc1[k] += wsum(cs1, p);
            acc2[k] += wsum(cs2, p);
            hp[base + p] = make_double2(acc1[k], acc2[k]);
        }
    }

    // block min/max -> one atomic pair per block into 64 cells
    for (int off = 32; off; off >>= 1) {
        lmin = fmin(lmin, __shfl_down(lmin, off));
        lmax = fmax(lmax, __shfl_down(lmax, off));
    }
    __shared__ double bmin[4], bmax[4];
    if (lane == 0) { bmin[w] = lmin; bmax[w] = lmax; }
    __syncthreads();
    if (t == 0) {
        double m0 = fmin(fmin(bmin[0], bmin[1]), fmin(bmin[2], bmin[3]));
        double m1 = fmax(fmax(bmax[0], bmax[1]), fmax(bmax[2], bmax[3]));
        int cell = blk & (NCELL - 1);
        atomicMin(&cells[cell], (unsigned long long)__double_as_longlong(m0));
        atomicMax(&cells[NCELL + cell], (unsigned long long)__double_as_longlong(m1));
    }
}

// Per-column exclusive prefix over slab totals: carry[b][s][col] = sum of
// C_loc(last row of s') for s' < s. One thread per (batch, column).
__global__ __launch_bounds__(256) void k1c_carry(const double2* __restrict__ hp,
                                                 double2* __restrict__ carry) {
    const int tid = blockIdx.x * 256 + threadIdx.x;   // 0 .. NB*IMW-1
    const int b = tid >> 10;
    const int col = tid & (IMW - 1);
    double a1 = 0.0, a2 = 0.0;
    #pragma unroll 8
    for (int s = 0; s < NSLAB; s++) {
        carry[((long long)b * NSLAB + s) * IMW + col] = make_double2(a1, a2);
        double2 v = hp[((long long)b * IMH + s * SLAB + SLAB - 1) * IMW + col];
        a1 += v.x;
        a2 += v.y;
    }
}

// Column pass, cumsum form: every output row independent.
// V(y) = Cv(y+25) - Cv(y-26) with reflect corrections; Cv = C_loc + carry.
__global__ __launch_bounds__(256) void k2_cpass(const float* __restrict__ in,
                                                const double2* __restrict__ hp,
                                                const double2* __restrict__ carry,
                                                const unsigned long long* __restrict__ cells,
                                                float* __restrict__ out) {
    __shared__ double sr[2];
    const int t = threadIdx.x;
    if (t < 64) {
        unsigned long long mn = cells[t];
        unsigned long long mx = cells[NCELL + t];
        for (int off = 32; off; off >>= 1) {
            unsigned long long a = __shfl_down(mn, off);
            unsigned long long b2 = __shfl_down(mx, off);
            mn = (a < mn) ? a : mn;
            mx = (b2 > mx) ? b2 : mx;
        }
        if (t == 0) {
            sr[0] = __longlong_as_double((long long)mn);
            sr[1] = __longlong_as_double((long long)mx);
        }
    }
    __syncthreads();
    const double r  = 0.5 * (sr[1] - sr[0]);
    const double r2 = r * r;

    const int id   = blockIdx.x;          // 2048 blocks
    const int b    = id & 7;              // batch -> XCD
    const int rest = id >> 3;
    const int ys   = rest & 63;           // y-strip (consecutive on same XCD)
    const int xt   = rest >> 6;           // x quarter (0..3)
    const int x  = xt * 256 + t;
    const int y0 = ys * STRIP;
    const long long ib = (long long)b * IMH * IMW;
    const double2* Cb = hp + ib;
    const double2* Kb = carry + (long long)b * NSLAB * IMW;

    #pragma unroll 2
    for (int y = y0; y < y0 + STRIP; y++) {
        const int top = (y + HALF > IMH - 1) ? (IMH - 1) : (y + HALF);
        const int bot = y - HALF - 1;

        double2 ct = Cb[(long long)top * IMW + x];
        double2 kt = Kb[(long long)(top >> 3) * IMW + x];
        double V1 = ct.x + kt.x;
        double V2 = ct.y + kt.y;
        if (bot >= 0) {
            double2 cbv = Cb[(long long)bot * IMW + x];
            double2 kbv = Kb[(long long)(bot >> 3) * IMW + x];
            V1 -= cbv.x + kbv.x;
            V2 -= cbv.y + kbv.y;
        }
        if (y <= HALF - 1) {   // top mirror: rows 1..25-y  => Cv(25-y) - Cv(0)
            int ma = HALF - y;
            double2 c1 = Cb[(long long)ma * IMW + x];
            double2 k1 = Kb[(long long)(ma >> 3) * IMW + x];
            double2 c0 = Cb[x];
            double2 k0 = Kb[x];
            V1 += (c1.x + k1.x) - (c0.x + k0.x);
            V2 += (c1.y + k1.y) - (c0.y + k0.y);
        }
        if (y + HALF > IMH - 1) {  // bottom mirror: rows [2*IMH-2-HALF-y .. IMH-2]
            int mz = 2 * IMH - 4 - HALF - y + 1;   // 2020 - y
            double2 c1 = Cb[(long long)(IMH - 2) * IMW + x];
            double2 k1 = Kb[(long long)((IMH - 2) >> 3) * IMW + x];
            double2 c0 = Cb[(long long)mz * IMW + x];
            double2 k0 = Kb[(long long)(mz >> 3) * IMW + x];
            V1 += (c1.x + k1.x) - (c0.x + k0.x);
            V2 += (c1.y + k1.y) - (c0.y + k0.y);
        }

        long long pix = ib + (long long)y * IMW + x;
        const float* p = in + pix * 3;
        double g = (double)p[0]*W_R + (double)p[1]*W_G + (double)p[2]*W_B;

        double m  = V1 * INV_AREA;
        double va = fmax(V2 * INV_AREA - m * m, 0.0);
        double A  = g - 0.8 * m;
        int o = (A > 0.0) && (A * A * r2 > 0.04 * m * m * va);
        out[pix] = o ? 1.0f : 0.0f;
    }
}

extern "C" void kernel_launch(void* const* d_in, const int* in_sizes, int n_in,
                              void* d_out, int out_size, void* d_ws, size_t ws_size,
                              hipStream_t stream) {
    const float* in = (const float*)d_in[0];
    float* out = (float*)d_out;

    unsigned long long* cells = (unsigned long long*)d_ws;      // 2*64 u64
    double2* hp = (double2*)((char*)d_ws + 4096);               // 134 MB C_loc {h1,h2}
    double2* carry = hp + (size_t)NB * IMH * IMW;               // 16.8 MB slab carries

    hipLaunchKernelGGL(k0_init, dim3(1), dim3(NCELL), 0, stream, cells);
    hipLaunchKernelGGL(k1_slab, dim3(NB * NSLAB), dim3(256), 0, stream,
                       in, hp, cells);
    hipLaunchKernelGGL(k1c_carry, dim3(NB * IMW / 256), dim3(256), 0, stream,
                       hp, carry);
    hipLaunchKernelGGL(k2_cpass, dim3((IMW / 256) * (IMH / STRIP) * NB), dim3(256), 0, stream,
                       in, hp, carry, cells, out);
}

// Round 9
// 262.176 us; speedup vs baseline: 1.0383x; 1.0383x over previous
//
#include <hip/hip_runtime.h>

#define IMW 1024
#define IMH 1024
#define NB  8
#define HALF 25
#define SLAB 8
#define NSLAB (IMH / SLAB)   // 128
#define STRIP 64
#define NSTRIP (IMH / STRIP) // 16
#define NCELL 64

#define W_R ((double)0.2989f)
#define W_G ((double)0.5870f)
#define W_B ((double)0.1140f)
#define INV_AREA (1.0 / 2601.0)

__device__ __forceinline__ int refl(int i, int n) {
    if (i < 0) i = -i;
    if (i >= n) i = 2 * n - 2 - i;
    return i;
}

// 51-window sum at pixel p from inclusive row cumsum C[0..IMW-1], reflect pad.
__device__ __forceinline__ double wsum(const double* __restrict__ C, int p) {
    int a = p + HALF; if (a > IMW - 1) a = IMW - 1;
    int b = p - HALF - 1;
    double s = C[a] - (b >= 0 ? C[b] : 0.0);
    if (p <= HALF - 1)      s += C[HALF - p] - C[0];                        // i<0 mirrored
    if (p >= IMW - HALF)    s += C[IMW - 2] - C[2*IMW - 2 - HALF - 1 - p];  // i>=IMW mirrored
    return s;
}

// init 64 min-cells (all-ones) and 64 max-cells (zero); gray>=0 so bit-order == double order
__global__ void k0_init(unsigned long long* cells) {
    cells[threadIdx.x] = ~0ULL;          // min cells
    cells[NCELL + threadIdx.x] = 0ULL;   // max cells
}

// One block per 8-row slab. Per row: horizontal cumsum scan, 51-window sums
// h1,h2 -> plain hp rows; accumulate 8-row slab sums Sv in registers (free).
__global__ __launch_bounds__(256) void k1_slab(const float* __restrict__ in,
                                               double2* __restrict__ hp,
                                               double2* __restrict__ Sv,
                                               unsigned long long* __restrict__ cells) {
    __shared__ double cs1[IMW];
    __shared__ double cs2[IMW];
    __shared__ double wt1[4], wt2[4];
    const int blk = blockIdx.x;                  // 0 .. NB*NSLAB-1
    const int b = blk / NSLAB;
    const int s = blk % NSLAB;
    const int r0 = s * SLAB;
    const int t = threadIdx.x;
    const int lane = t & 63, w = t >> 6;

    double s1[4] = {0.0, 0.0, 0.0, 0.0};
    double s2[4] = {0.0, 0.0, 0.0, 0.0};
    double lmin = 1e300, lmax = -1e300;

    for (int r = 0; r < SLAB; r++) {
        const int row = r0 + r;
        const long long base = ((long long)b * IMH + row) * IMW;

        // 4 consecutive pixels per thread = 12 floats = 3x float4
        const float4* p4 = (const float4*)(in + base * 3);
        float4 f0 = p4[3*t], f1 = p4[3*t+1], f2 = p4[3*t+2];
        double g0 = (double)f0.x*W_R + (double)f0.y*W_G + (double)f0.z*W_B;
        double g1 = (double)f0.w*W_R + (double)f1.x*W_G + (double)f1.y*W_B;
        double g2 = (double)f1.z*W_R + (double)f1.w*W_G + (double)f2.x*W_B;
        double g3 = (double)f2.y*W_R + (double)f2.z*W_G + (double)f2.w*W_B;

        double l1_0 = g0, l1_1 = l1_0 + g1, l1_2 = l1_1 + g2, l1_3 = l1_2 + g3;
        double q0 = g0*g0, q1 = g1*g1, q2 = g2*g2, q3 = g3*g3;
        double l2_0 = q0, l2_1 = l2_0 + q1, l2_2 = l2_1 + q2, l2_3 = l2_2 + q3;

        lmin = fmin(lmin, fmin(fmin(g0, g1), fmin(g2, g3)));
        lmax = fmax(lmax, fmax(fmax(g0, g1), fmax(g2, g3)));

        // wave-level inclusive scan of per-thread totals
        double v1 = l1_3, v2 = l2_3;
        for (int off = 1; off < 64; off <<= 1) {
            double u1 = __shfl_up(v1, off);
            double u2 = __shfl_up(v2, off);
            if (lane >= off) { v1 += u1; v2 += u2; }
        }
        __syncthreads();                 // cs/wt free from previous row
        if (lane == 63) { wt1[w] = v1; wt2[w] = v2; }
        __syncthreads();
        double e1 = v1 - l1_3, e2 = v2 - l2_3;
        for (int j = 0; j < w; j++) { e1 += wt1[j]; e2 += wt2[j]; }

        double2* c1 = (double2*)&cs1[4*t];
        double2* c2 = (double2*)&cs2[4*t];
        c1[0] = make_double2(e1 + l1_0, e1 + l1_1);
        c1[1] = make_double2(e1 + l1_2, e1 + l1_3);
        c2[0] = make_double2(e2 + l2_0, e2 + l2_1);
        c2[1] = make_double2(e2 + l2_2, e2 + l2_3);
        __syncthreads();                 // cs ready

        #pragma unroll
        for (int k = 0; k < 4; k++) {
            int p = t + 256 * k;
            double h1 = wsum(cs1, p);
            double h2 = wsum(cs2, p);
            hp[base + p] = make_double2(h1, h2);
            s1[k] += h1;
            s2[k] += h2;
        }
    }

    // slab sums (free: already in registers)
    #pragma unroll
    for (int k = 0; k < 4; k++) {
        int p = t + 256 * k;
        Sv[((long long)b * NSLAB + s) * IMW + p] = make_double2(s1[k], s2[k]);
    }

    // block min/max -> one atomic pair per block into 64 cells
    for (int off = 32; off; off >>= 1) {
        lmin = fmin(lmin, __shfl_down(lmin, off));
        lmax = fmax(lmax, __shfl_down(lmax, off));
    }
    __shared__ double bmin[4], bmax[4];
    if (lane == 0) { bmin[w] = lmin; bmax[w] = lmax; }
    __syncthreads();
    if (t == 0) {
        double m0 = fmin(fmin(bmin[0], bmin[1]), fmin(bmin[2], bmin[3]));
        double m1 = fmax(fmax(bmax[0], bmax[1]), fmax(bmax[2], bmax[3]));
        int cell = blk & (NCELL - 1);
        atomicMin(&cells[cell], (unsigned long long)__double_as_longlong(m0));
        atomicMax(&cells[NCELL + cell], (unsigned long long)__double_as_longlong(m1));
    }
}

// sum of h rows a..b (both in [0,IMH-1]) for column x, using slab sums where
// possible: partial edges read h directly, full 8-row slabs read Sv.
__device__ __forceinline__ void sum_rows(const double2* __restrict__ Hb,
                                         const double2* __restrict__ Svb,
                                         int a, int b, int x,
                                         double& V1, double& V2) {
    int r = a;
    while ((r & 7) && r <= b) {
        double2 h = Hb[(long long)r * IMW + x];
        V1 += h.x; V2 += h.y; r++;
    }
    while (r + 7 <= b) {
        double2 s = Svb[(long long)(r >> 3) * IMW + x];
        V1 += s.x; V2 += s.y; r += 8;
    }
    while (r <= b) {
        double2 h = Hb[(long long)r * IMW + x];
        V1 += h.x; V2 += h.y; r++;
    }
}

// Column pass: running 51-window sum, V0 init from slab sums (~9 reads instead
// of 51), steady state 2 h-rows/output = 48 B/pix logical.
__global__ __launch_bounds__(256) void k2_colpass(const float* __restrict__ in,
                                                  const double2* __restrict__ hp,
                                                  const double2* __restrict__ Sv,
                                                  const unsigned long long* __restrict__ cells,
                                                  float* __restrict__ out) {
    __shared__ double sr[2];
    const int t = threadIdx.x;
    if (t < 64) {
        unsigned long long mn = cells[t];
        unsigned long long mx = cells[NCELL + t];
        for (int off = 32; off; off >>= 1) {
            unsigned long long a = __shfl_down(mn, off);
            unsigned long long b2 = __shfl_down(mx, off);
            mn = (a < mn) ? a : mn;
            mx = (b2 > mx) ? b2 : mx;
        }
        if (t == 0) {
            sr[0] = __longlong_as_double((long long)mn);
            sr[1] = __longlong_as_double((long long)mx);
        }
    }
    __syncthreads();
    const double r  = 0.5 * (sr[1] - sr[0]);
    const double r2 = r * r;

    const int id   = blockIdx.x;          // 512 blocks
    const int b    = id & 7;              // batch -> XCD
    const int rest = id >> 3;
    const int ys   = rest & (NSTRIP - 1); // y-strip (consecutive on same XCD)
    const int xt   = rest >> 4;           // x quarter (0..3)
    const int x  = xt * 256 + t;
    const int y0 = ys * STRIP;
    const long long ib = (long long)b * IMH * IMW;
    const double2* Hb  = hp + ib;
    const double2* Svb = Sv + (long long)b * NSLAB * IMW;

    // V0 = sum_{j=-25..25} h(refl(y0+j)); y0+25 <= 985 so only low mirror.
    double V1 = 0.0, V2 = 0.0;
    const int lo = y0 - HALF, hi = y0 + HALF;
    sum_rows(Hb, Svb, lo < 0 ? 0 : lo, hi, x, V1, V2);
    if (lo < 0) sum_rows(Hb, Svb, 1, -lo, x, V1, V2);

    #pragma unroll 8
    for (int y = y0; y < y0 + STRIP; y++) {
        long long pix = ib + (long long)y * IMW + x;
        const float* p = in + pix * 3;
        double g = (double)p[0]*W_R + (double)p[1]*W_G + (double)p[2]*W_B;

        double m  = V1 * INV_AREA;
        double va = fmax(V2 * INV_AREA - m * m, 0.0);
        double A  = g - 0.8 * m;
        int o = (A > 0.0) && (A * A * r2 > 0.04 * m * m * va);
        out[pix] = o ? 1.0f : 0.0f;

        if (y + 1 < y0 + STRIP) {
            int ra = refl(y + HALF + 1, IMH);
            int rs = refl(y - HALF, IMH);
            double2 ha = Hb[(long long)ra * IMW + x];
            double2 hs = Hb[(long long)rs * IMW + x];
            V1 += ha.x - hs.x;
            V2 += ha.y - hs.y;
        }
    }
}

extern "C" void kernel_launch(void* const* d_in, const int* in_sizes, int n_in,
                              void* d_out, int out_size, void* d_ws, size_t ws_size,
                              hipStream_t stream) {
    const float* in = (const float*)d_in[0];
    float* out = (float*)d_out;

    unsigned long long* cells = (unsigned long long*)d_ws;      // 2*64 u64
    double2* hp = (double2*)((char*)d_ws + 4096);               // 134 MB plain {h1,h2}
    double2* Sv = hp + (size_t)NB * IMH * IMW;                  // 16.8 MB slab sums

    hipLaunchKernelGGL(k0_init, dim3(1), dim3(NCELL), 0, stream, cells);
    hipLaunchKernelGGL(k1_slab, dim3(NB * NSLAB), dim3(256), 0, stream,
                       in, hp, Sv, cells);
    hipLaunchKernelGGL(k2_colpass, dim3((IMW / 256) * NSTRIP * NB), dim3(256), 0, stream,
                       in, hp, Sv, cells, out);
}